// Round 5
// baseline (221.483 us; speedup 1.0000x reference)
//
#include <hip/hip_runtime.h>
#include <hip/hip_bf16.h>

// CAM: per batch b (B=16):  a = x[b] viewed as [N=4096, C=256]
//   aTa = a^T a [C,C]; attn = softmax(aTa, -1); out = gamma*(a·attn) + x
// Storage fp32 (bf16-grid values). Internal bf16 MFMA / fp32 accum.
//
// R5 structure: BARRIER-FREE GEMMs. MFMA fragments are loaded directly
// global->VGPR (16 B/lane, the 4 quads of a row tile to exactly one 64 B
// line -> fully coalesced). No LDS, no __syncthreads in either GEMM: R4
// showed both were latency-bound (MfmaUtil ~7%, all pipes idle) on the
// stage->barrier->MFMA->barrier structure with tiny K panels.
// k_prep emits aT (transposed bf16) for gemm1 and xbf (row-major bf16)
// for gemm2's A-side + residual (bit-exact: values are on the bf16 grid).

#define BB 16
#define NN 4096   // H*W
#define CC 256
#define SPLITK 8
#define KCHUNK (NN / SPLITK)   // 512

typedef __attribute__((ext_vector_type(4))) short short4v;
typedef __attribute__((ext_vector_type(8))) short short8v;
typedef __attribute__((ext_vector_type(4))) float floatx4;

__device__ __forceinline__ unsigned short f2bf(float f) {
    unsigned int u = __float_as_uint(f);
    u += 0x7fffu + ((u >> 16) & 1u);   // RNE (exact for bf16-grid values)
    return (unsigned short)(u >> 16);
}
__device__ __forceinline__ float bf2f(unsigned short u) {
    return __uint_as_float(((unsigned int)u) << 16);
}
__device__ __forceinline__ short4v cvt4(floatx4 v) {
    short4v r;
    r[0] = (short)f2bf(v[0]); r[1] = (short)f2bf(v[1]);
    r[2] = (short)f2bf(v[2]); r[3] = (short)f2bf(v[3]);
    return r;
}

// ------- K0: aT[b][c][n] = bf16(x[b][n][c]);  xbf[b][n][c] = bf16(x) ----
__global__ __launch_bounds__(256) void k_prep(const float* __restrict__ x,
                                              unsigned short* __restrict__ aT,
                                              unsigned short* __restrict__ xbf) {
    __shared__ unsigned short tile[64 * 68];
    const int b  = blockIdx.z;
    const int n0 = blockIdx.x * 64;
    const int c0 = blockIdx.y * 64;
    const int t  = threadIdx.x;
    const int q4 = (t & 15) * 4;
    const int tr = t >> 4;

    const float* xb = x + ((size_t)b * NN + n0) * CC + c0;
    unsigned short* xbfb = xbf + ((size_t)b * NN + n0) * CC + c0;
    for (int r = 0; r < 4; ++r) {
        int row = tr + 16 * r;
        floatx4 v = *(const floatx4*)(xb + (size_t)row * CC + q4);
        short4v s = cvt4(v);
        *(short4v*)&tile[row * 68 + q4] = s;
        *(short4v*)(xbfb + (size_t)row * CC + q4) = s;
    }
    __syncthreads();
    unsigned short* aTb = aT + ((size_t)b * CC + c0) * NN + n0;
    for (int r = 0; r < 4; ++r) {
        int c = tr + 16 * r;
        short4v v;
        v[0] = (short)tile[(q4 + 0) * 68 + c];
        v[1] = (short)tile[(q4 + 1) * 68 + c];
        v[2] = (short)tile[(q4 + 2) * 68 + c];
        v[3] = (short)tile[(q4 + 3) * 68 + c];
        *(short4v*)(aTb + (size_t)c * NN + q4) = v;
    }
}

// ------- K1: part[split][b] = partial a^T a  (no LDS, no barriers) ------
// grid (4, BB, SPLITK) = 512 blocks. Wave w: 64x64 slice (i0..+63, w*64..+63),
// 4x4 accs. Frags loaded straight from aT: lane lm picks the row, quad picks
// the 16 B k-chunk -> one 64 B line per row per 32-k step.
__global__ __launch_bounds__(256) void k_gemm1(const unsigned short* __restrict__ aT,
                                               float* __restrict__ part) {
    const int i0    = blockIdx.x * 64;
    const int b     = blockIdx.y;
    const int split = blockIdx.z;
    const int t  = threadIdx.x;
    const int w  = t >> 6, l = t & 63;
    const int lk = (l >> 4) * 8;
    const int lm = l & 15;

    const unsigned short* arow[4];
    const unsigned short* brow[4];
    #pragma unroll
    for (int mt = 0; mt < 4; ++mt)
        arow[mt] = aT + ((size_t)b * CC + i0 + mt * 16 + lm) * NN + lk;
    #pragma unroll
    for (int nt = 0; nt < 4; ++nt)
        brow[nt] = aT + ((size_t)b * CC + w * 64 + nt * 16 + lm) * NN + lk;

    floatx4 acc[4][4] = {};
    const int kbeg = split * KCHUNK;
    #pragma unroll 4
    for (int k0 = kbeg; k0 < kbeg + KCHUNK; k0 += 32) {
        short8v af[4], bf[4];
        #pragma unroll
        for (int mt = 0; mt < 4; ++mt) af[mt] = *(const short8v*)(arow[mt] + k0);
        #pragma unroll
        for (int nt = 0; nt < 4; ++nt) bf[nt] = *(const short8v*)(brow[nt] + k0);
        #pragma unroll
        for (int mt = 0; mt < 4; ++mt)
            #pragma unroll
            for (int nt = 0; nt < 4; ++nt)
                acc[mt][nt] = __builtin_amdgcn_mfma_f32_16x16x32_bf16(af[mt], bf[nt], acc[mt][nt], 0, 0, 0);
    }
    const int orow = (l >> 4) * 4;   // C/D: row=(lane>>4)*4+r, col=lane&15
    float* pout = part + ((size_t)(split * BB + b) * CC) * CC;
    #pragma unroll
    for (int mt = 0; mt < 4; ++mt)
        #pragma unroll
        for (int nt = 0; nt < 4; ++nt)
            #pragma unroll
            for (int r = 0; r < 4; ++r) {
                int i = i0 + mt * 16 + orow + r;
                int j = w * 64 + nt * 16 + lm;
                pout[(size_t)i * CC + j] = acc[mt][nt][r];
            }
}

// ------- K2: attn_T[b][j][i] = softmax over summed partials -------------
__global__ __launch_bounds__(256) void k_softmax(const float* __restrict__ part,
                                                 unsigned short* __restrict__ attnT) {
    const int w = threadIdx.x >> 6;
    const int l = threadIdx.x & 63;
    const int row = blockIdx.x * 4 + w;   // 0..B*C-1
    const int b = row >> 8;
    const int i = row & 255;
    float v0 = 0.f, v1 = 0.f, v2 = 0.f, v3 = 0.f;
    #pragma unroll
    for (int s = 0; s < SPLITK; ++s) {
        const float* p = part + ((size_t)(s * BB + b) * CC + i) * CC;
        v0 += p[l]; v1 += p[l + 64]; v2 += p[l + 128]; v3 += p[l + 192];
    }
    float m = fmaxf(fmaxf(v0, v1), fmaxf(v2, v3));
    for (int off = 32; off >= 1; off >>= 1) m = fmaxf(m, __shfl_xor(m, off, 64));
    v0 = __expf(v0 - m); v1 = __expf(v1 - m); v2 = __expf(v2 - m); v3 = __expf(v3 - m);
    float s = v0 + v1 + v2 + v3;
    for (int off = 32; off >= 1; off >>= 1) s += __shfl_xor(s, off, 64);
    float rs = 1.0f / s;
    unsigned short* o = attnT + (size_t)b * CC * CC + i;   // attnT[b][j][i]
    o[(size_t)(l +   0) * CC] = f2bf(v0 * rs);
    o[(size_t)(l +  64) * CC] = f2bf(v1 * rs);
    o[(size_t)(l + 128) * CC] = f2bf(v2 * rs);
    o[(size_t)(l + 192) * CC] = f2bf(v3 * rs);
}

// ------- K3: out = gamma * (a · attn) + x  (no LDS, no barriers) --------
// grid (64, BB) = 1024 blocks = 4/CU (launch_bounds caps VGPR for 16 w/CU).
// A frags from xbf (bf16 row-major), B frags from attnT, residual from xbf.
__global__ __launch_bounds__(256, 4) void k_gemm2(const unsigned short* __restrict__ xbf,
                                                  const unsigned short* __restrict__ attnT,
                                                  const float* __restrict__ gamma,
                                                  float* __restrict__ out) {
    const int n0 = blockIdx.x * 64;
    const int b  = blockIdx.y;
    const int t  = threadIdx.x;
    const int w  = t >> 6, l = t & 63;
    const int lk = (l >> 4) * 8, lm = l & 15;

    const unsigned short* arow[4];
    const unsigned short* brow[4];
    #pragma unroll
    for (int mt = 0; mt < 4; ++mt)
        arow[mt] = xbf + ((size_t)b * NN + n0 + mt * 16 + lm) * CC + lk;
    #pragma unroll
    for (int nt = 0; nt < 4; ++nt)
        brow[nt] = attnT + ((size_t)b * CC + w * 64 + nt * 16 + lm) * CC + lk;

    floatx4 acc[4][4] = {};
    #pragma unroll
    for (int k0 = 0; k0 < CC; k0 += 32) {
        short8v af[4], bf[4];
        #pragma unroll
        for (int mt = 0; mt < 4; ++mt) af[mt] = *(const short8v*)(arow[mt] + k0);
        #pragma unroll
        for (int nt = 0; nt < 4; ++nt) bf[nt] = *(const short8v*)(brow[nt] + k0);
        #pragma unroll
        for (int mt = 0; mt < 4; ++mt)
            #pragma unroll
            for (int nt = 0; nt < 4; ++nt)
                acc[mt][nt] = __builtin_amdgcn_mfma_f32_16x16x32_bf16(af[mt], bf[nt], acc[mt][nt], 0, 0, 0);
    }
    const float g = gamma[0];
    const int orow = (l >> 4) * 4;
    #pragma unroll
    for (int mt = 0; mt < 4; ++mt)
        #pragma unroll
        for (int nt = 0; nt < 4; ++nt)
            #pragma unroll
            for (int r = 0; r < 4; ++r) {
                int nr = n0 + mt * 16 + orow + r;
                int j  = w * 64 + nt * 16 + lm;
                size_t idx = ((size_t)b * NN + nr) * CC + j;
                out[idx] = g * acc[mt][nt][r] + bf2f(xbf[idx]);   // L1-warm
            }
}

extern "C" void kernel_launch(void* const* d_in, const int* in_sizes, int n_in,
                              void* d_out, int out_size, void* d_ws, size_t ws_size,
                              hipStream_t stream) {
    const float* x     = (const float*)d_in[0];
    const float* gamma = (const float*)d_in[1];
    float* out = (float*)d_out;

    char* ws = (char*)d_ws;
    unsigned short* aT    = (unsigned short*)ws;                              // 32 MB
    unsigned short* xbf   = (unsigned short*)(ws + (size_t)32 * 1024 * 1024); // 32 MB
    float*          part  = (float*)(ws + (size_t)64 * 1024 * 1024);          // 32 MB
    unsigned short* attnT = (unsigned short*)(ws + (size_t)96 * 1024 * 1024); // 2 MB

    k_prep   <<<dim3(NN / 64, CC / 64, BB), 256, 0, stream>>>(x, aT, xbf);
    k_gemm1  <<<dim3(CC / 64, BB, SPLITK),  256, 0, stream>>>(aT, part);
    k_softmax<<<dim3(BB * CC / 4),          256, 0, stream>>>(part, attnT);
    k_gemm2  <<<dim3(NN / 64, BB),          256, 0, stream>>>(xbf, attnT, gamma, out);
}